// Round 3
// baseline (189.347 us; speedup 1.0000x reference)
//
#include <hip/hip_runtime.h>

#define BB 16
#define CCH 256
#define WWD 64
#define HHT 64
#define WH (WWD*HHT)   // 4096

typedef short bf16x8 __attribute__((ext_vector_type(8)));
typedef float f32x4  __attribute__((ext_vector_type(4)));

// RNE float -> bf16 bit pattern (inputs are finite normals; NaN not handled)
__device__ __forceinline__ short f2bf(float f) {
  unsigned u = __builtin_bit_cast(unsigned, f);
  u += 0x7fffu + ((u >> 16) & 1u);
  return (short)(u >> 16);
}
__device__ __forceinline__ float bf2f(short s) {
  unsigned u = ((unsigned)(unsigned short)s) << 16;
  return __builtin_bit_cast(float, u);
}

__global__ __launch_bounds__(256) void selfattn_kernel(
    const float* __restrict__ x, const float* __restrict__ Wq,
    const float* __restrict__ Wk, float* __restrict__ out) {
  // LDS: q [64][36] fp32 (padded), k [32][64] fp32, attnT [64][64] packed (bf16 hi|lo<<16)
  __shared__ float    q_lds[64 * 36];
  __shared__ float    k_lds[32 * 64];
  __shared__ unsigned attnT[64 * 64];

  const int tid  = threadIdx.x;
  const int lane = tid & 63;
  const int wave = tid >> 6;
  const int blk  = blockIdx.x;
  const int b    = blk >> 6;
  const int w    = blk & 63;

  const float* xb = x   + (size_t)b * CCH * WH + (size_t)w * HHT;
  float*       ob = out + (size_t)b * CCH * WH + (size_t)w * HHT;

  // ---------------- Phase 1: q[h][d], k[d][j], fp32 VALU ---------------------
  const int d0 = __builtin_amdgcn_readfirstlane(wave * 8);
  float qa[8] = {0,0,0,0,0,0,0,0};
  float ka[8] = {0,0,0,0,0,0,0,0};
  for (int cb = 0; cb < CCH; cb += 32) {
    float xv[32];
    #pragma unroll
    for (int cc = 0; cc < 32; ++cc) xv[cc] = xb[(size_t)(cb + cc) * WH + lane];
    #pragma unroll
    for (int dd = 0; dd < 8; ++dd) {
      const float4* wq4 = (const float4*)(Wq + (size_t)(d0 + dd) * CCH + cb);  // uniform
      const float4* wk4 = (const float4*)(Wk + (size_t)(d0 + dd) * CCH + cb);  // uniform
      float qacc = qa[dd], kacc = ka[dd];
      #pragma unroll
      for (int c4 = 0; c4 < 8; ++c4) {
        const float4 wq = wq4[c4];
        const float4 wk = wk4[c4];
        qacc += xv[4*c4+0]*wq.x + xv[4*c4+1]*wq.y + xv[4*c4+2]*wq.z + xv[4*c4+3]*wq.w;
        kacc += xv[4*c4+0]*wk.x + xv[4*c4+1]*wk.y + xv[4*c4+2]*wk.z + xv[4*c4+3]*wk.w;
      }
      qa[dd] = qacc; ka[dd] = kacc;
    }
  }
  #pragma unroll
  for (int dd = 0; dd < 8; ++dd) {
    q_lds[lane*36 + d0 + dd] = qa[dd];      // [h][d], pad 36
    k_lds[(d0+dd)*64 + lane] = ka[dd];      // [d][j]
  }
  __syncthreads();

  // ---------------- Phase 2: energy + softmax (lane = j), pack attn hi/lo ----
  float kc[32];
  #pragma unroll
  for (int d = 0; d < 32; ++d) kc[d] = k_lds[d*64 + lane];

  const int h0 = __builtin_amdgcn_readfirstlane(wave * 16);
  for (int hh = 0; hh < 16; ++hh) {
    const int h = h0 + hh;
    const float4* qrow = (const float4*)&q_lds[h*36];   // wave-uniform broadcast
    float e = 0.f;
    #pragma unroll
    for (int d4 = 0; d4 < 8; ++d4) {
      const float4 qv = qrow[d4];
      e += qv.x*kc[4*d4+0] + qv.y*kc[4*d4+1] + qv.z*kc[4*d4+2] + qv.w*kc[4*d4+3];
    }
    float m = e;
    #pragma unroll
    for (int off = 32; off >= 1; off >>= 1) m = fmaxf(m, __shfl_xor(m, off, 64));
    const float ex = __expf(e - m);
    float s = ex;
    #pragma unroll
    for (int off = 32; off >= 1; off >>= 1) s += __shfl_xor(s, off, 64);
    const float p  = ex / s;                 // attn[h][j=lane]
    const short ph = f2bf(p);
    const short pl = f2bf(p - bf2f(ph));
    // attn[h][j] stored at [j][h ^ (j&31)] — conflict-free write & read
    attnT[lane*64 + (h ^ (lane & 31))] =
        (unsigned)(unsigned short)ph | ((unsigned)(unsigned short)pl << 16);
  }
  __syncthreads();

  // ---------------- Phase 3: PV via split-bf16 MFMA --------------------------
  // out[c][i] = sum_j x[c][j]*attn[i][j];  C = A(x,256x64) @ B(attn^T,64x64)
  // A frag: lane holds A[l&15][(l>>4)*8+t]; B frag: B[(l>>4)*8+t][l&15];
  // C/D: row=(l>>4)*4+r, col=l&15  (m89-verified)
  const int g   = lane >> 4;
  const int r16 = lane & 15;

  // Preload all B fragments (attn hi/lo), reused across all 4 c-tiles.
  bf16x8 bh[4][2], bl[4][2];
  #pragma unroll
  for (int it = 0; it < 4; ++it) {
    const int i = it*16 + r16;
    #pragma unroll
    for (int ks = 0; ks < 2; ++ks) {
      bf16x8 hfr, lfr;
      #pragma unroll
      for (int t = 0; t < 8; ++t) {
        const int j = ks*32 + g*8 + t;
        const unsigned pw = attnT[j*64 + (i ^ (j & 31))];
        hfr[t] = (short)(pw & 0xffffu);
        lfr[t] = (short)(pw >> 16);
      }
      bh[it][ks] = hfr; bl[it][ks] = lfr;
    }
  }

  const int c0w = __builtin_amdgcn_readfirstlane(wave * 64);
  #pragma unroll
  for (int ct = 0; ct < 4; ++ct) {
    const int crow = c0w + ct*16 + r16;     // A-operand row for this lane
    bf16x8 xh[2], xl[2];
    #pragma unroll
    for (int ks = 0; ks < 2; ++ks) {
      const float4 f0 = *(const float4*)(xb + (size_t)crow*WH + ks*32 + g*8);
      const float4 f1 = *(const float4*)(xb + (size_t)crow*WH + ks*32 + g*8 + 4);
      const float xs[8] = {f0.x,f0.y,f0.z,f0.w,f1.x,f1.y,f1.z,f1.w};
      bf16x8 hfr, lfr;
      #pragma unroll
      for (int t = 0; t < 8; ++t) {
        hfr[t] = f2bf(xs[t]);
        lfr[t] = f2bf(xs[t] - bf2f(hfr[t]));
      }
      xh[ks] = hfr; xl[ks] = lfr;
    }
    #pragma unroll
    for (int it = 0; it < 4; ++it) {
      f32x4 acc = {0.f, 0.f, 0.f, 0.f};
      #pragma unroll
      for (int ks = 0; ks < 2; ++ks) {
        acc = __builtin_amdgcn_mfma_f32_16x16x32_bf16(xh[ks], bh[it][ks], acc, 0, 0, 0);
        acc = __builtin_amdgcn_mfma_f32_16x16x32_bf16(xh[ks], bl[it][ks], acc, 0, 0, 0);
        acc = __builtin_amdgcn_mfma_f32_16x16x32_bf16(xl[ks], bh[it][ks], acc, 0, 0, 0);
      }
      const int i = it*16 + r16;
      #pragma unroll
      for (int r = 0; r < 4; ++r) {
        const int c = c0w + ct*16 + g*4 + r;
        const float xg = xb[(size_t)c*WH + i];
        ob[(size_t)c*WH + i] = acc[r] * xg;   // elementwise gate
      }
    }
  }
}

extern "C" void kernel_launch(void* const* d_in, const int* in_sizes, int n_in,
                              void* d_out, int out_size, void* d_ws, size_t ws_size,
                              hipStream_t stream) {
  (void)in_sizes; (void)n_in; (void)d_ws; (void)ws_size; (void)out_size;
  const float* x  = (const float*)d_in[0];
  const float* Wq = (const float*)d_in[1];
  const float* Wk = (const float*)d_in[2];
  float* out = (float*)d_out;
  dim3 grid(BB * WWD);   // 1024 blocks: one per (b, w)
  dim3 block(256);
  hipLaunchKernelGGL(selfattn_kernel, grid, block, 0, stream, x, Wq, Wk, out);
}

// Round 4
// 153.401 us; speedup vs baseline: 1.2343x; 1.2343x over previous
//
#include <hip/hip_runtime.h>

#define BB 16
#define CCH 256
#define WWD 64
#define HHT 64
#define WH (WWD*HHT)   // 4096

typedef short bf16x8 __attribute__((ext_vector_type(8)));
typedef float f32x4  __attribute__((ext_vector_type(4)));

// RNE float -> bf16 bit pattern (finite inputs)
__device__ __forceinline__ short f2bf(float f) {
  unsigned u = __builtin_bit_cast(unsigned, f);
  u += 0x7fffu + ((u >> 16) & 1u);
  return (short)(u >> 16);
}
__device__ __forceinline__ float bf2f(short s) {
  unsigned u = ((unsigned)(unsigned short)s) << 16;
  return __builtin_bit_cast(float, u);
}

// ---------------------------------------------------------------------------
// Pre-kernel: pack W' = [Wq;Wk] (64 x 256) into MFMA A-fragments, split bf16.
// Layout: hi frags at ws[0..16383] (shorts), lo frags at ws[16384..32767].
// Frag id f = mt*8+kt; element (f, lane, t) holds W'[mt*16+(lane&15)][kt*32+(lane>>4)*8+t].
// ---------------------------------------------------------------------------
__global__ __launch_bounds__(256) void wsplit_kernel(
    const float* __restrict__ Wq, const float* __restrict__ Wk,
    short* __restrict__ ws) {
  const int gid    = blockIdx.x * 256 + threadIdx.x;   // 0..2047
  const int fragid = gid >> 6;
  const int lane   = gid & 63;
  const int dp = (fragid >> 3) * 16 + (lane & 15);     // d' in 0..63
  const int cb = (fragid & 7) * 32 + ((lane >> 4) & 3) * 8;
  const float* Wrow = (dp < 32) ? (Wq + (size_t)dp * CCH)
                                : (Wk + (size_t)(dp - 32) * CCH);
  bf16x8 hfr, lfr;
  #pragma unroll
  for (int t = 0; t < 8; ++t) {
    const float v = Wrow[cb + t];
    const short h = f2bf(v);
    hfr[t] = h;
    lfr[t] = f2bf(v - bf2f(h));
  }
  *(bf16x8*)(ws + (size_t)gid * 8)         = hfr;
  *(bf16x8*)(ws + 16384 + (size_t)gid * 8) = lfr;
}

// ---------------------------------------------------------------------------
// Main kernel: one block per (b, w).
// ---------------------------------------------------------------------------
__global__ __launch_bounds__(256, 4) void selfattn_kernel(
    const float* __restrict__ x, const short* __restrict__ ws,
    float* __restrict__ out) {
  __shared__ float    q_lds[64 * 36];   // [h][d], pad 36
  __shared__ float    k_lds[32 * 64];   // [d][h]
  __shared__ unsigned attnT[64 * 64];   // [j][i^ (j&31)] packed bf16 hi|lo

  const int tid  = threadIdx.x;
  const int lane = tid & 63;
  const int wave = tid >> 6;
  const int g    = lane >> 4;
  const int r16  = lane & 15;
  const int blk  = blockIdx.x;
  const int b    = blk >> 6;
  const int w    = blk & 63;

  const float* xb = x   + (size_t)b * CCH * WH + (size_t)w * HHT;
  float*       ob = out + (size_t)b * CCH * WH + (size_t)w * HHT;

  // ---------------- Phase 1: projections via split-bf16 MFMA -----------------
  // C[d'][h] = sum_c W'[d'][c] * x[c][h];  M=64 (d'), N=64 (h), K=256.
  // This wave owns n-tile nt = wave (16 h columns).
  {
    const int nt = wave;
    // B-frags (x), kt = 0..7, converted to split bf16 in registers.
    bf16x8 xbh[8], xbl[8];
    #pragma unroll
    for (int kt = 0; kt < 8; ++kt) {
      bf16x8 hfr, lfr;
      #pragma unroll
      for (int t = 0; t < 8; ++t) {
        const int c = kt*32 + g*8 + t;
        const float v = xb[(size_t)c * WH + nt*16 + r16];
        const short h = f2bf(v);
        hfr[t] = h;
        lfr[t] = f2bf(v - bf2f(h));
      }
      xbh[kt] = hfr; xbl[kt] = lfr;
    }
    const short* wsh = ws;
    const short* wsl = ws + 16384;
    #pragma unroll
    for (int mt = 0; mt < 4; ++mt) {
      f32x4 acc = {0.f, 0.f, 0.f, 0.f};
      #pragma unroll
      for (int kt = 0; kt < 8; ++kt) {
        const bf16x8 ah = *(const bf16x8*)(wsh + (size_t)((mt*8 + kt)*64 + lane) * 8);
        const bf16x8 al = *(const bf16x8*)(wsl + (size_t)((mt*8 + kt)*64 + lane) * 8);
        acc = __builtin_amdgcn_mfma_f32_16x16x32_bf16(ah, xbh[kt], acc, 0, 0, 0);
        acc = __builtin_amdgcn_mfma_f32_16x16x32_bf16(ah, xbl[kt], acc, 0, 0, 0);
        acc = __builtin_amdgcn_mfma_f32_16x16x32_bf16(al, xbh[kt], acc, 0, 0, 0);
      }
      // C/D layout: row d' = mt*16 + g*4 + r, col h = nt*16 + r16
      #pragma unroll
      for (int r = 0; r < 4; ++r) {
        const int dp = mt*16 + g*4 + r;
        const int h  = nt*16 + r16;
        if (mt < 2) q_lds[h*36 + dp] = acc[r];
        else        k_lds[(dp - 32)*64 + h] = acc[r];
      }
    }
  }
  __syncthreads();

  // ---------------- Phase 2: energy + softmax (lane = j), pack attn hi/lo ----
  float kc[32];
  #pragma unroll
  for (int d = 0; d < 32; ++d) kc[d] = k_lds[d*64 + lane];

  const int h0 = __builtin_amdgcn_readfirstlane(wave * 16);
  for (int hh = 0; hh < 16; ++hh) {
    const int h = h0 + hh;
    const float4* qrow = (const float4*)&q_lds[h*36];   // wave-uniform broadcast
    float e = 0.f;
    #pragma unroll
    for (int d4 = 0; d4 < 8; ++d4) {
      const float4 qv = qrow[d4];
      e += qv.x*kc[4*d4+0] + qv.y*kc[4*d4+1] + qv.z*kc[4*d4+2] + qv.w*kc[4*d4+3];
    }
    float m = e;
    #pragma unroll
    for (int off = 32; off >= 1; off >>= 1) m = fmaxf(m, __shfl_xor(m, off, 64));
    const float ex = __expf(e - m);
    float s = ex;
    #pragma unroll
    for (int off = 32; off >= 1; off >>= 1) s += __shfl_xor(s, off, 64);
    const float p  = ex / s;                 // attn[h][j=lane]
    const short ph = f2bf(p);
    const short pl = f2bf(p - bf2f(ph));
    attnT[lane*64 + (h ^ (lane & 31))] =
        (unsigned)(unsigned short)ph | ((unsigned)(unsigned short)pl << 16);
  }
  __syncthreads();

  // ---------------- Phase 3: PV via split-bf16 MFMA --------------------------
  // out[c][i] = sum_j x[c][j]*attn[i][j];  C = A(x,256x64) @ B(attn^T,64x64)
  bf16x8 bh[4][2], bl[4][2];
  #pragma unroll
  for (int it = 0; it < 4; ++it) {
    const int i = it*16 + r16;
    #pragma unroll
    for (int ks = 0; ks < 2; ++ks) {
      bf16x8 hfr, lfr;
      #pragma unroll
      for (int t = 0; t < 8; ++t) {
        const int j = ks*32 + g*8 + t;
        const unsigned pw = attnT[j*64 + (i ^ (j & 31))];
        hfr[t] = (short)(pw & 0xffffu);
        lfr[t] = (short)(pw >> 16);
      }
      bh[it][ks] = hfr; bl[it][ks] = lfr;
    }
  }

  const int c0w = __builtin_amdgcn_readfirstlane(wave * 64);
  #pragma unroll
  for (int ct = 0; ct < 4; ++ct) {
    const int crow = c0w + ct*16 + r16;     // A-operand row for this lane
    bf16x8 xh[2], xl[2];
    #pragma unroll
    for (int ks = 0; ks < 2; ++ks) {
      const float4 f0 = *(const float4*)(xb + (size_t)crow*WH + ks*32 + g*8);
      const float4 f1 = *(const float4*)(xb + (size_t)crow*WH + ks*32 + g*8 + 4);
      const float xs[8] = {f0.x,f0.y,f0.z,f0.w,f1.x,f1.y,f1.z,f1.w};
      bf16x8 hfr, lfr;
      #pragma unroll
      for (int t = 0; t < 8; ++t) {
        hfr[t] = f2bf(xs[t]);
        lfr[t] = f2bf(xs[t] - bf2f(hfr[t]));
      }
      xh[ks] = hfr; xl[ks] = lfr;
    }
    #pragma unroll
    for (int it = 0; it < 4; ++it) {
      f32x4 acc = {0.f, 0.f, 0.f, 0.f};
      #pragma unroll
      for (int ks = 0; ks < 2; ++ks) {
        acc = __builtin_amdgcn_mfma_f32_16x16x32_bf16(xh[ks], bh[it][ks], acc, 0, 0, 0);
        acc = __builtin_amdgcn_mfma_f32_16x16x32_bf16(xh[ks], bl[it][ks], acc, 0, 0, 0);
        acc = __builtin_amdgcn_mfma_f32_16x16x32_bf16(xl[ks], bh[it][ks], acc, 0, 0, 0);
      }
      const int i = it*16 + r16;
      #pragma unroll
      for (int r = 0; r < 4; ++r) {
        const int c = c0w + ct*16 + g*4 + r;
        const float xg = xb[(size_t)c*WH + i];
        ob[(size_t)c*WH + i] = acc[r] * xg;   // elementwise gate
      }
    }
  }
}

// ---------------------------------------------------------------------------
// Fallback (proven round-3 kernel) if ws is too small for the W frag buffer.
// ---------------------------------------------------------------------------
__global__ __launch_bounds__(256) void selfattn_fb(
    const float* __restrict__ x, const float* __restrict__ Wq,
    const float* __restrict__ Wk, float* __restrict__ out) {
  __shared__ float    q_lds[64 * 36];
  __shared__ float    k_lds[32 * 64];
  __shared__ unsigned attnT[64 * 64];

  const int tid  = threadIdx.x;
  const int lane = tid & 63;
  const int wave = tid >> 6;
  const int blk  = blockIdx.x;
  const int b    = blk >> 6;
  const int w    = blk & 63;

  const float* xb = x   + (size_t)b * CCH * WH + (size_t)w * HHT;
  float*       ob = out + (size_t)b * CCH * WH + (size_t)w * HHT;

  const int d0 = __builtin_amdgcn_readfirstlane(wave * 8);
  float qa[8] = {0,0,0,0,0,0,0,0};
  float ka[8] = {0,0,0,0,0,0,0,0};
  for (int cb = 0; cb < CCH; cb += 32) {
    float xv[32];
    #pragma unroll
    for (int cc = 0; cc < 32; ++cc) xv[cc] = xb[(size_t)(cb + cc) * WH + lane];
    #pragma unroll
    for (int dd = 0; dd < 8; ++dd) {
      const float4* wq4 = (const float4*)(Wq + (size_t)(d0 + dd) * CCH + cb);
      const float4* wk4 = (const float4*)(Wk + (size_t)(d0 + dd) * CCH + cb);
      float qacc = qa[dd], kacc = ka[dd];
      #pragma unroll
      for (int c4 = 0; c4 < 8; ++c4) {
        const float4 wq = wq4[c4];
        const float4 wk = wk4[c4];
        qacc += xv[4*c4+0]*wq.x + xv[4*c4+1]*wq.y + xv[4*c4+2]*wq.z + xv[4*c4+3]*wq.w;
        kacc += xv[4*c4+0]*wk.x + xv[4*c4+1]*wk.y + xv[4*c4+2]*wk.z + xv[4*c4+3]*wk.w;
      }
      qa[dd] = qacc; ka[dd] = kacc;
    }
  }
  #pragma unroll
  for (int dd = 0; dd < 8; ++dd) {
    q_lds[lane*36 + d0 + dd] = qa[dd];
    k_lds[(d0+dd)*64 + lane] = ka[dd];
  }
  __syncthreads();

  float kc[32];
  #pragma unroll
  for (int d = 0; d < 32; ++d) kc[d] = k_lds[d*64 + lane];

  const int h0 = __builtin_amdgcn_readfirstlane(wave * 16);
  for (int hh = 0; hh < 16; ++hh) {
    const int h = h0 + hh;
    const float4* qrow = (const float4*)&q_lds[h*36];
    float e = 0.f;
    #pragma unroll
    for (int d4 = 0; d4 < 8; ++d4) {
      const float4 qv = qrow[d4];
      e += qv.x*kc[4*d4+0] + qv.y*kc[4*d4+1] + qv.z*kc[4*d4+2] + qv.w*kc[4*d4+3];
    }
    float m = e;
    #pragma unroll
    for (int off = 32; off >= 1; off >>= 1) m = fmaxf(m, __shfl_xor(m, off, 64));
    const float ex = __expf(e - m);
    float s = ex;
    #pragma unroll
    for (int off = 32; off >= 1; off >>= 1) s += __shfl_xor(s, off, 64);
    const float p  = ex / s;
    const short ph = f2bf(p);
    const short pl = f2bf(p - bf2f(ph));
    attnT[lane*64 + (h ^ (lane & 31))] =
        (unsigned)(unsigned short)ph | ((unsigned)(unsigned short)pl << 16);
  }
  __syncthreads();

  const int g   = lane >> 4;
  const int r16 = lane & 15;
  bf16x8 bh[4][2], bl[4][2];
  #pragma unroll
  for (int it = 0; it < 4; ++it) {
    const int i = it*16 + r16;
    #pragma unroll
    for (int ks = 0; ks < 2; ++ks) {
      bf16x8 hfr, lfr;
      #pragma unroll
      for (int t = 0; t < 8; ++t) {
        const int j = ks*32 + g*8 + t;
        const unsigned pw = attnT[j*64 + (i ^ (j & 31))];
        hfr[t] = (short)(pw & 0xffffu);
        lfr[t] = (short)(pw >> 16);
      }
      bh[it][ks] = hfr; bl[it][ks] = lfr;
    }
  }

  const int c0w = __builtin_amdgcn_readfirstlane(wave * 64);
  #pragma unroll
  for (int ct = 0; ct < 4; ++ct) {
    const int crow = c0w + ct*16 + r16;
    bf16x8 xh[2], xl[2];
    #pragma unroll
    for (int ks = 0; ks < 2; ++ks) {
      const float4 f0 = *(const float4*)(xb + (size_t)crow*WH + ks*32 + g*8);
      const float4 f1 = *(const float4*)(xb + (size_t)crow*WH + ks*32 + g*8 + 4);
      const float xs[8] = {f0.x,f0.y,f0.z,f0.w,f1.x,f1.y,f1.z,f1.w};
      bf16x8 hfr, lfr;
      #pragma unroll
      for (int t = 0; t < 8; ++t) {
        hfr[t] = f2bf(xs[t]);
        lfr[t] = f2bf(xs[t] - bf2f(hfr[t]));
      }
      xh[ks] = hfr; xl[ks] = lfr;
    }
    #pragma unroll
    for (int it = 0; it < 4; ++it) {
      f32x4 acc = {0.f, 0.f, 0.f, 0.f};
      #pragma unroll
      for (int ks = 0; ks < 2; ++ks) {
        acc = __builtin_amdgcn_mfma_f32_16x16x32_bf16(xh[ks], bh[it][ks], acc, 0, 0, 0);
        acc = __builtin_amdgcn_mfma_f32_16x16x32_bf16(xh[ks], bl[it][ks], acc, 0, 0, 0);
        acc = __builtin_amdgcn_mfma_f32_16x16x32_bf16(xl[ks], bh[it][ks], acc, 0, 0, 0);
      }
      const int i = it*16 + r16;
      #pragma unroll
      for (int r = 0; r < 4; ++r) {
        const int c = c0w + ct*16 + g*4 + r;
        const float xg = xb[(size_t)c*WH + i];
        ob[(size_t)c*WH + i] = acc[r] * xg;
      }
    }
  }
}

extern "C" void kernel_launch(void* const* d_in, const int* in_sizes, int n_in,
                              void* d_out, int out_size, void* d_ws, size_t ws_size,
                              hipStream_t stream) {
  (void)in_sizes; (void)n_in; (void)out_size;
  const float* x  = (const float*)d_in[0];
  const float* Wq = (const float*)d_in[1];
  const float* Wk = (const float*)d_in[2];
  float* out = (float*)d_out;
  if (ws_size >= 65536) {
    hipLaunchKernelGGL(wsplit_kernel, dim3(8), dim3(256), 0, stream,
                       Wq, Wk, (short*)d_ws);
    hipLaunchKernelGGL(selfattn_kernel, dim3(BB * WWD), dim3(256), 0, stream,
                       x, (const short*)d_ws, out);
  } else {
    hipLaunchKernelGGL(selfattn_fb, dim3(BB * WWD), dim3(256), 0, stream,
                       x, Wq, Wk, out);
  }
}